// Round 1
// baseline (221.825 us; speedup 1.0000x reference)
//
#include <hip/hip_runtime.h>

// Problem constants (fixed by the reference): x[8192][4096] fp32,
// A[16][4096], B[4096][16], A0[16][4096], B0[4096][16], scaling = 16/16 = 1.
#define N_TOK 8192
#define D     4096
#define RLO   16
#define R2    32          // combined rank (B path + B0 path)
#define KS    4           // split-K factor for stage 1
#define KSPAN (D / KS)    // 1024
#define SCALING 1.0f

// d_ws layout (floats):
//   PT [R2][D]            : P^T, PT[r][k] = B[k][r] (r<16) / -B0[k][r-16]
//   Qs [R2][D]            : Qs[r][j] = s*A[r][j] (r<16) / s*A0[r-16][j]
//   UP [KS][N_TOK][R2]    : split-K partials of u = x @ P
// total = 2*32*4096 + 4*8192*32 floats = 5 MB

__global__ __launch_bounds__(256) void prep_kernel(
    const float* __restrict__ A, const float* __restrict__ B,
    const float* __restrict__ A0, const float* __restrict__ B0,
    float* __restrict__ PT, float* __restrict__ Qs) {
  int idx = blockIdx.x * 256 + threadIdx.x;   // 0 .. 32*4096-1
  int r = idx >> 12;          // row of PT/Qs
  int k = idx & (D - 1);      // col
  float pt, q;
  if (r < RLO) {
    pt = B[k * RLO + r];
    q  = SCALING * A[r * D + k];
  } else {
    pt = -B0[k * RLO + (r - RLO)];
    q  = SCALING * A0[(r - RLO) * D + k];
  }
  PT[idx] = pt;
  Qs[idx] = q;
}

// Stage 1: u[i][r] = sum_k x[i][k] * PT[r][k], split-K over KS segments.
// Wave layout: lane = 64 lanes -> r = lane&31, h = lane>>5 (k-quad half).
// Each wave register-tiles 8 rows; block = 4 waves = 32 rows.
__global__ __launch_bounds__(256) void s1_kernel(
    const float* __restrict__ x, const float* __restrict__ PT,
    float* __restrict__ UP) {
  const int tid  = threadIdx.x;
  const int wave = tid >> 6;
  const int lane = tid & 63;
  const int r    = lane & 31;
  const int h    = lane >> 5;
  const int bx   = blockIdx.x;
  const int kseg   = bx & (KS - 1);
  const int rowblk = bx >> 2;              // KS == 4
  const int i0    = rowblk * 32 + wave * 8;
  const int kbase = kseg * KSPAN + 4 * h;

  const float* pt = PT + (size_t)r * D + kbase;
  const float* xr = x + (size_t)i0 * D + kbase;

  float acc[8] = {0.f, 0.f, 0.f, 0.f, 0.f, 0.f, 0.f, 0.f};
  for (int k = 0; k < KSPAN; k += 8) {
    const float4 p = *(const float4*)(pt + k);
#pragma unroll
    for (int i = 0; i < 8; ++i) {
      const float4 xv = *(const float4*)(xr + (size_t)i * D + k);
      acc[i] = fmaf(xv.x, p.x, acc[i]);
      acc[i] = fmaf(xv.y, p.y, acc[i]);
      acc[i] = fmaf(xv.z, p.z, acc[i]);
      acc[i] = fmaf(xv.w, p.w, acc[i]);
    }
  }
  // combine the two k-quad halves of the wave
#pragma unroll
  for (int i = 0; i < 8; ++i)
    acc[i] += __shfl_xor(acc[i], 32, 64);
  if (h == 0) {
#pragma unroll
    for (int i = 0; i < 8; ++i)
      UP[((size_t)kseg * N_TOK + (i0 + i)) * R2 + r] = acc[i];
  }
}

// Stage 2: out[i][j] = sum_r u[i][r] * Qs[r][j].
// Block: 256 threads, 8-row x 1024-col tile; thread: 8 rows x float4 cols.
__global__ __launch_bounds__(256) void s2_kernel(
    const float* __restrict__ UP, const float* __restrict__ Qs,
    float* __restrict__ out) {
  __shared__ __align__(16) float us[8][R2];
  const int tid   = threadIdx.x;
  const int bx    = blockIdx.x;
  const int jblk  = bx & 3;
  const int itile = bx >> 2;
  const int i0 = itile * 8;
  const int j0 = jblk * 1024 + tid * 4;

  {  // u-tile preload: 256 threads -> 8x32 values, summing KS partials
    const int i = tid >> 5;
    const int r = tid & 31;
    float s = 0.f;
#pragma unroll
    for (int ks = 0; ks < KS; ++ks)
      s += UP[((size_t)ks * N_TOK + (i0 + i)) * R2 + r];
    us[i][r] = s;
  }
  __syncthreads();

  float4 acc[8];
#pragma unroll
  for (int i = 0; i < 8; ++i) acc[i] = make_float4(0.f, 0.f, 0.f, 0.f);

  for (int r0 = 0; r0 < R2; r0 += 4) {
    const float4 q0 = *(const float4*)(Qs + (size_t)(r0 + 0) * D + j0);
    const float4 q1 = *(const float4*)(Qs + (size_t)(r0 + 1) * D + j0);
    const float4 q2 = *(const float4*)(Qs + (size_t)(r0 + 2) * D + j0);
    const float4 q3 = *(const float4*)(Qs + (size_t)(r0 + 3) * D + j0);
#pragma unroll
    for (int i = 0; i < 8; ++i) {
      const float4 uv = *(const float4*)(&us[i][r0]);
      acc[i].x = fmaf(uv.x, q0.x, acc[i].x);
      acc[i].y = fmaf(uv.x, q0.y, acc[i].y);
      acc[i].z = fmaf(uv.x, q0.z, acc[i].z);
      acc[i].w = fmaf(uv.x, q0.w, acc[i].w);
      acc[i].x = fmaf(uv.y, q1.x, acc[i].x);
      acc[i].y = fmaf(uv.y, q1.y, acc[i].y);
      acc[i].z = fmaf(uv.y, q1.z, acc[i].z);
      acc[i].w = fmaf(uv.y, q1.w, acc[i].w);
      acc[i].x = fmaf(uv.z, q2.x, acc[i].x);
      acc[i].y = fmaf(uv.z, q2.y, acc[i].y);
      acc[i].z = fmaf(uv.z, q2.z, acc[i].z);
      acc[i].w = fmaf(uv.z, q2.w, acc[i].w);
      acc[i].x = fmaf(uv.w, q3.x, acc[i].x);
      acc[i].y = fmaf(uv.w, q3.y, acc[i].y);
      acc[i].z = fmaf(uv.w, q3.z, acc[i].z);
      acc[i].w = fmaf(uv.w, q3.w, acc[i].w);
    }
  }
#pragma unroll
  for (int i = 0; i < 8; ++i)
    *(float4*)(out + (size_t)(i0 + i) * D + j0) = acc[i];
}

extern "C" void kernel_launch(void* const* d_in, const int* in_sizes, int n_in,
                              void* d_out, int out_size, void* d_ws, size_t ws_size,
                              hipStream_t stream) {
  const float* x  = (const float*)d_in[0];
  const float* A  = (const float*)d_in[1];
  const float* B  = (const float*)d_in[2];
  const float* A0 = (const float*)d_in[3];
  const float* B0 = (const float*)d_in[4];
  float* out = (float*)d_out;

  float* ws = (float*)d_ws;
  float* PT = ws;                    // 32*4096
  float* Qs = ws + R2 * D;           // 32*4096
  float* UP = ws + 2 * R2 * D;       // KS*8192*32

  hipLaunchKernelGGL(prep_kernel, dim3((R2 * D) / 256), dim3(256), 0, stream,
                     A, B, A0, B0, PT, Qs);
  hipLaunchKernelGGL(s1_kernel, dim3((N_TOK / 32) * KS), dim3(256), 0, stream,
                     x, PT, UP);
  hipLaunchKernelGGL(s2_kernel, dim3((N_TOK / 8) * 4), dim3(256), 0, stream,
                     UP, Qs, out);
}

// Round 3
// 132.427 us; speedup vs baseline: 1.6751x; 1.6751x over previous
//
#include <hip/hip_runtime.h>

// out = x @ ((B@A - B0@A0) * s)  ==  ((x@[B|-B0]) @ [A;A0]) * s
// x[8192][4096] fp32, A/A0[16][4096], B/B0[4096][16], s = 16/16 = 1.
#define N_TOK 8192
#define D     4096
#define RLO   16
#define R2    32          // combined rank
#define KS    16          // split-K segments for stage 1
#define KSEG  256         // D / KS
#define RPB   128         // rows per s1 block
#define BUFR  16          // rows per staged LDS buffer
#define NBUF  (RPB / BUFR)
#define SCALING 1.0f

// d_ws layout (floats):
//   PT [R2][D]           : PT[r][k] = B[k][r] (r<16) / -B0[k][r-16]
//   Qs [R2][D]           : Qs[r][j] = s*A[r][j] (r<16) / s*A0[r-16][j]
//   UP [KS][N_TOK][R2]   : split-K partials of u = x @ P   (16 MB)

__global__ __launch_bounds__(256) void prep_kernel(
    const float* __restrict__ A, const float* __restrict__ B,
    const float* __restrict__ A0, const float* __restrict__ B0,
    float* __restrict__ PT, float* __restrict__ Qs) {
  int idx = blockIdx.x * 256 + threadIdx.x;   // 0 .. 32*4096-1
  int r = idx >> 12;
  int k = idx & (D - 1);
  float pt, q;
  if (r < RLO) {
    pt = B[k * RLO + r];
    q  = SCALING * A[r * D + k];
  } else {
    pt = -B0[k * RLO + (r - RLO)];
    q  = SCALING * A0[(r - RLO) * D + k];
  }
  PT[idx] = pt;
  Qs[idx] = q;
}

// Stage 1: UP[kseg][i][r] = sum_{k in kseg} x[i][k] * PT[r][k]
// Block: 4 waves, one 256-k segment, 128 rows.
// Wave w owns r-span w*8..w*8+7. Lane = h*32+m: half h takes even/odd row of a
// pair; lane's 8 k are {m*4..m*4+3} and {128+m*4..128+m*4+7} (contiguous
// across lanes -> coalesced global loads and conflict-free LDS reads).
__global__ __launch_bounds__(256, 3) void s1_kernel(
    const float* __restrict__ x, const float* __restrict__ PT,
    float* __restrict__ UP) {
  __shared__ __align__(16) float xbuf[2][BUFR][KSEG];   // 32 KB
  const int tid  = threadIdx.x;
  const int w    = tid >> 6;
  const int lane = tid & 63;
  const int h    = lane >> 5;
  const int m    = lane & 31;
  const int kseg = blockIdx.x & (KS - 1);
  const int rowblk = blockIdx.x >> 4;          // KS == 16
  const int row0 = rowblk * RPB;
  const int ksb  = kseg * KSEG;

  // PT fragment in registers: 8 r x (4+4) k
  float4 ptA[8], ptB[8];
  {
    const float* pb = PT + (size_t)(w * 8) * D + ksb;
#pragma unroll
    for (int j = 0; j < 8; ++j) {
      ptA[j] = *(const float4*)(pb + (size_t)j * D + m * 4);
      ptB[j] = *(const float4*)(pb + (size_t)j * D + 128 + m * 4);
    }
  }

  // Cooperative staging: 256 threads x 4 x float4 = one 16-row buffer.
  // Per c: wave covers one row slot with a contiguous 1 KB span.
  float4 sreg[4];
  auto stage_load = [&](int rbase) {
#pragma unroll
    for (int c = 0; c < 4; ++c) {
      int idx  = c * 256 + tid;
      int slot = idx >> 6;
      int col  = (idx & 63) * 4;
      sreg[c] = *(const float4*)(x + (size_t)(row0 + rbase + slot) * D + ksb + col);
    }
  };
  auto stage_write = [&](int b) {
#pragma unroll
    for (int c = 0; c < 4; ++c) {
      int idx  = c * 256 + tid;
      int slot = idx >> 6;
      int col  = (idx & 63) * 4;
      *(float4*)&xbuf[b][slot][col] = sreg[c];
    }
  };

  const bool b16 = (m & 16) != 0, b8 = (m & 8) != 0, b4 = (m & 4) != 0;

  auto compute = [&](int b, int rbase) {
#pragma unroll
    for (int p = 0; p < BUFR / 2; ++p) {
      const int rp = 2 * p + h;
      const float4 xa = *(const float4*)&xbuf[b][rp][m * 4];
      const float4 xb = *(const float4*)&xbuf[b][rp][128 + m * 4];
      float v[8];
#pragma unroll
      for (int j = 0; j < 8; ++j) {
        float a;
        a = xa.x * ptA[j].x;
        a = fmaf(xa.y, ptA[j].y, a);
        a = fmaf(xa.z, ptA[j].z, a);
        a = fmaf(xa.w, ptA[j].w, a);
        a = fmaf(xb.x, ptB[j].x, a);
        a = fmaf(xb.y, ptB[j].y, a);
        a = fmaf(xb.z, ptB[j].z, a);
        a = fmaf(xb.w, ptB[j].w, a);
        v[j] = a;
      }
      // split-butterfly: 8 vals over 32-lane half -> 1 val, r-bits on m4,m3,m2
#pragma unroll
      for (int j = 0; j < 4; ++j) {
        float send = b16 ? v[j] : v[j + 4];
        float keep = b16 ? v[j + 4] : v[j];
        v[j] = keep + __shfl_xor(send, 16, 64);
      }
#pragma unroll
      for (int j = 0; j < 2; ++j) {
        float send = b8 ? v[j] : v[j + 2];
        float keep = b8 ? v[j + 2] : v[j];
        v[j] = keep + __shfl_xor(send, 8, 64);
      }
      {
        float send = b4 ? v[0] : v[1];
        float keep = b4 ? v[1] : v[0];
        v[0] = keep + __shfl_xor(send, 4, 64);
      }
      v[0] += __shfl_xor(v[0], 2, 64);
      v[0] += __shfl_xor(v[0], 1, 64);
      if ((m & 3) == 0) {
        int rl = m >> 2;   // = m4*4 + m3*2 + m2 for writer lanes
        UP[((size_t)kseg * N_TOK + (row0 + rbase + rp)) * R2 + w * 8 + rl] = v[0];
      }
    }
  };

  stage_load(0);
  stage_write(0);
  __syncthreads();
#pragma unroll
  for (int it = 0; it < NBUF; ++it) {
    if (it + 1 < NBUF) stage_load((it + 1) * BUFR);   // loads overlap compute
    compute(it & 1, it * BUFR);
    if (it + 1 < NBUF) stage_write((it + 1) & 1);     // other buffer: no hazard
    __syncthreads();
  }
}

// Stage 2: out[i][j] = sum_r (sum_ks UP[ks][i][r]) * Qs[r][j]
__global__ __launch_bounds__(256) void s2_kernel(
    const float* __restrict__ UP, const float* __restrict__ Qs,
    float* __restrict__ out) {
  __shared__ __align__(16) float us[8][R2];
  const int tid   = threadIdx.x;
  const int bx    = blockIdx.x;
  const int jblk  = bx & 3;
  const int itile = bx >> 2;
  const int i0 = itile * 8;
  const int j0 = jblk * 1024 + tid * 4;

  {  // u-tile preload: 8x32 values, summing KS partials
    const int i = tid >> 5;
    const int r = tid & 31;
    float s = 0.f;
#pragma unroll
    for (int ks = 0; ks < KS; ++ks)
      s += UP[((size_t)ks * N_TOK + (i0 + i)) * R2 + r];
    us[i][r] = s;
  }
  __syncthreads();

  float4 acc[8];
#pragma unroll
  for (int i = 0; i < 8; ++i) acc[i] = make_float4(0.f, 0.f, 0.f, 0.f);

  for (int r0 = 0; r0 < R2; r0 += 4) {
    const float4 q0 = *(const float4*)(Qs + (size_t)(r0 + 0) * D + j0);
    const float4 q1 = *(const float4*)(Qs + (size_t)(r0 + 1) * D + j0);
    const float4 q2 = *(const float4*)(Qs + (size_t)(r0 + 2) * D + j0);
    const float4 q3 = *(const float4*)(Qs + (size_t)(r0 + 3) * D + j0);
#pragma unroll
    for (int i = 0; i < 8; ++i) {
      const float4 uv = *(const float4*)(&us[i][r0]);
      acc[i].x = fmaf(uv.x, q0.x, acc[i].x);
      acc[i].y = fmaf(uv.x, q0.y, acc[i].y);
      acc[i].z = fmaf(uv.x, q0.z, acc[i].z);
      acc[i].w = fmaf(uv.x, q0.w, acc[i].w);
      acc[i].x = fmaf(uv.y, q1.x, acc[i].x);
      acc[i].y = fmaf(uv.y, q1.y, acc[i].y);
      acc[i].z = fmaf(uv.y, q1.z, acc[i].z);
      acc[i].w = fmaf(uv.y, q1.w, acc[i].w);
      acc[i].x = fmaf(uv.z, q2.x, acc[i].x);
      acc[i].y = fmaf(uv.z, q2.y, acc[i].y);
      acc[i].z = fmaf(uv.z, q2.z, acc[i].z);
      acc[i].w = fmaf(uv.z, q2.w, acc[i].w);
      acc[i].x = fmaf(uv.w, q3.x, acc[i].x);
      acc[i].y = fmaf(uv.w, q3.y, acc[i].y);
      acc[i].z = fmaf(uv.w, q3.z, acc[i].z);
      acc[i].w = fmaf(uv.w, q3.w, acc[i].w);
    }
  }
#pragma unroll
  for (int i = 0; i < 8; ++i)
    *(float4*)(out + (size_t)(i0 + i) * D + j0) = acc[i];
}

extern "C" void kernel_launch(void* const* d_in, const int* in_sizes, int n_in,
                              void* d_out, int out_size, void* d_ws, size_t ws_size,
                              hipStream_t stream) {
  const float* x  = (const float*)d_in[0];
  const float* A  = (const float*)d_in[1];
  const float* B  = (const float*)d_in[2];
  const float* A0 = (const float*)d_in[3];
  const float* B0 = (const float*)d_in[4];
  float* out = (float*)d_out;

  float* ws = (float*)d_ws;
  float* PT = ws;                    // 32*4096
  float* Qs = ws + R2 * D;           // 32*4096
  float* UP = ws + 2 * R2 * D;       // KS*8192*32 = 4M floats

  hipLaunchKernelGGL(prep_kernel, dim3((R2 * D) / 256), dim3(256), 0, stream,
                     A, B, A0, B0, PT, Qs);
  hipLaunchKernelGGL(s1_kernel, dim3(KS * (N_TOK / RPB)), dim3(256), 0, stream,
                     x, PT, UP);
  hipLaunchKernelGGL(s2_kernel, dim3((N_TOK / 8) * 4), dim3(256), 0, stream,
                     UP, Qs, out);
}

// Round 5
// 79.995 us; speedup vs baseline: 2.7730x; 1.6554x over previous
//
#include <hip/hip_runtime.h>

// out = x @ ((B@A - B0@A0) * s)  ==  ((x@[B|-B0]) @ [A;A0]) * s,  s = 1.
// x[8192][4096] fp32, A/A0[16][4096], B/B0[4096][16].
// Both GEMMs run on mfma_f32_16x16x32_bf16 (fp32 accumulate); all K-reduction
// happens in the matrix pipe -> no cross-lane shuffles at all.
#define N_TOK 8192
#define D     4096
#define RLO   16
#define R2    32
#define KSL   16          // UP partial slices (4 outer ksegs x 4 waves)

typedef __bf16  bf16x8  __attribute__((ext_vector_type(8)));
typedef short   short8v __attribute__((ext_vector_type(8)));
typedef float   f32x4   __attribute__((ext_vector_type(4)));

__device__ __forceinline__ short bf1(float f) {
  __bf16 b = (__bf16)f;
  return __builtin_bit_cast(short, b);
}

__device__ __forceinline__ short8v cvt8(float4 lo, float4 hi) {
  bf16x8 b;
  b[0] = (__bf16)lo.x; b[1] = (__bf16)lo.y; b[2] = (__bf16)lo.z; b[3] = (__bf16)lo.w;
  b[4] = (__bf16)hi.x; b[5] = (__bf16)hi.y; b[6] = (__bf16)hi.z; b[7] = (__bf16)hi.w;
  return __builtin_bit_cast(short8v, b);
}

// d_ws layout: PTb [32][4096] bf16 (256 KB) | Qpk [4096][32] bf16 (256 KB)
//              | UP [16][8192][32] fp32 (16 MB)

__global__ __launch_bounds__(256) void prep_kernel(
    const float* __restrict__ A, const float* __restrict__ B,
    const float* __restrict__ A0, const float* __restrict__ B0,
    ushort* __restrict__ PTb, ushort* __restrict__ Qpk) {
  int idx = blockIdx.x * 256 + threadIdx.x;   // 0 .. 32*4096-1
  int r = idx >> 12;
  int k = idx & (D - 1);
  float pt, q;
  if (r < RLO) {
    pt = B[k * RLO + r];
    q  = A[r * D + k];
  } else {
    pt = -B0[k * RLO + (r - RLO)];
    q  = A0[(r - RLO) * D + k];
  }
  PTb[idx] = (ushort)bf1(pt);                 // [r][k], k contiguous
  Qpk[(size_t)k * R2 + r] = (ushort)bf1(q);   // [j][r], r contiguous
}

// Stage 1: UP[kw][i][r] = sum_{k in slice} x[i][k] * P[k][r]
// Block: 4 waves x 32 rows; wave w owns a 256-k slice, kw = kout*4+w.
// Per k-step (K=32): A-frag lane l: x[row0 + (l&15) (+16)][kb + (l>>4)*8 + j]
//                    B-frag lane l: PTb[(l&15) (+16)][kb + (l>>4)*8 + j]
__global__ __launch_bounds__(256) void s1_kernel(
    const float* __restrict__ x, const ushort* __restrict__ PTb,
    float* __restrict__ UP) {
  const int tid  = threadIdx.x;
  const int w    = tid >> 6;
  const int lane = tid & 63;
  const int l16  = lane & 15;
  const int kg   = lane >> 4;
  const int rowblk = blockIdx.x & 255;
  const int kout   = blockIdx.x >> 8;          // 0..3
  const int row0 = rowblk * 32;
  const int kb   = kout * 1024 + w * 256 + kg * 8;

  const float*  xp0 = x   + (size_t)(row0 + l16) * D + kb;
  const float*  xp1 = xp0 + (size_t)16 * D;
  const ushort* pb0 = PTb + (size_t)l16 * D + kb;
  const ushort* pb1 = pb0 + (size_t)16 * D;

  f32x4 acc00 = {0.f, 0.f, 0.f, 0.f};
  f32x4 acc01 = {0.f, 0.f, 0.f, 0.f};
  f32x4 acc10 = {0.f, 0.f, 0.f, 0.f};
  f32x4 acc11 = {0.f, 0.f, 0.f, 0.f};

#pragma unroll
  for (int s = 0; s < 8; ++s) {
    const int ko = s * 32;
    const float4 a0l = *(const float4*)(xp0 + ko);
    const float4 a0h = *(const float4*)(xp0 + ko + 4);
    const float4 a1l = *(const float4*)(xp1 + ko);
    const float4 a1h = *(const float4*)(xp1 + ko + 4);
    const short8v b0 = *(const short8v*)(pb0 + ko);
    const short8v b1 = *(const short8v*)(pb1 + ko);
    const short8v a0 = cvt8(a0l, a0h);
    const short8v a1 = cvt8(a1l, a1h);
    acc00 = __builtin_amdgcn_mfma_f32_16x16x32_bf16(a0, b0, acc00, 0, 0, 0);
    acc01 = __builtin_amdgcn_mfma_f32_16x16x32_bf16(a0, b1, acc01, 0, 0, 0);
    acc10 = __builtin_amdgcn_mfma_f32_16x16x32_bf16(a1, b0, acc10, 0, 0, 0);
    acc11 = __builtin_amdgcn_mfma_f32_16x16x32_bf16(a1, b1, acc11, 0, 0, 0);
  }

  // D-frag: col = lane&15, row = (lane>>4)*4 + j
  float* up = UP + ((size_t)(kout * 4 + w) * N_TOK + row0) * R2;
#pragma unroll
  for (int j = 0; j < 4; ++j) {
    up[(kg * 4 + j) * R2 + l16]             = acc00[j];
    up[(kg * 4 + j) * R2 + 16 + l16]        = acc01[j];
    up[(16 + kg * 4 + j) * R2 + l16]        = acc10[j];
    up[(16 + kg * 4 + j) * R2 + 16 + l16]   = acc11[j];
  }
}

// Stage 2: out[i][j] = sum_r u[i][r] * Q[r][j], u = sum of 16 UP slices.
// Block: 32 rows x 1024 j (4 waves x 256 j). K = R2 = 32 -> one MFMA depth.
__global__ __launch_bounds__(256) void s2_kernel(
    const float* __restrict__ UP, const ushort* __restrict__ Qpk,
    float* __restrict__ out) {
  __shared__ __align__(16) ushort usb[32][R2];   // u in bf16, row-major, 2 KB
  const int tid = threadIdx.x;
  const int rowblk = (int)blockIdx.x >> 2;       // 0..255
  const int jseg   = blockIdx.x & 3;
  const int row0 = rowblk * 32;

  {  // sum 16 fp32 partials -> bf16 u tile (coalesced float4 reads)
    const int row = tid >> 3;
    const int r4  = (tid & 7) * 4;
    float4 s = make_float4(0.f, 0.f, 0.f, 0.f);
#pragma unroll
    for (int ks = 0; ks < KSL; ++ks) {
      const float4 v = *(const float4*)(UP + ((size_t)ks * N_TOK + row0 + row) * R2 + r4);
      s.x += v.x; s.y += v.y; s.z += v.z; s.w += v.w;
    }
    usb[row][r4 + 0] = (ushort)bf1(s.x);
    usb[row][r4 + 1] = (ushort)bf1(s.y);
    usb[row][r4 + 2] = (ushort)bf1(s.z);
    usb[row][r4 + 3] = (ushort)bf1(s.w);
  }
  __syncthreads();

  const int w    = tid >> 6;
  const int lane = tid & 63;
  const int l16  = lane & 15;
  const int kg   = lane >> 4;
  const int jbase = jseg * 1024 + w * 256;

  const short8v ua0 = *(const short8v*)&usb[l16][kg * 8];
  const short8v ua1 = *(const short8v*)&usb[16 + l16][kg * 8];
  const f32x4 z = {0.f, 0.f, 0.f, 0.f};

#pragma unroll
  for (int jt = 0; jt < 16; ++jt) {
    const int j = jbase + jt * 16 + l16;
    const short8v qb = *(const short8v*)(Qpk + (size_t)j * R2 + kg * 8);
    const f32x4 d0 = __builtin_amdgcn_mfma_f32_16x16x32_bf16(ua0, qb, z, 0, 0, 0);
    const f32x4 d1 = __builtin_amdgcn_mfma_f32_16x16x32_bf16(ua1, qb, z, 0, 0, 0);
    float* o = out + (size_t)(row0 + kg * 4) * D + j;
#pragma unroll
    for (int jr = 0; jr < 4; ++jr) {
      o[(size_t)jr * D]        = d0[jr];
      o[(size_t)(16 + jr) * D] = d1[jr];
    }
  }
}

extern "C" void kernel_launch(void* const* d_in, const int* in_sizes, int n_in,
                              void* d_out, int out_size, void* d_ws, size_t ws_size,
                              hipStream_t stream) {
  const float* x  = (const float*)d_in[0];
  const float* A  = (const float*)d_in[1];
  const float* B  = (const float*)d_in[2];
  const float* A0 = (const float*)d_in[3];
  const float* B0 = (const float*)d_in[4];
  float* out = (float*)d_out;

  ushort* PTb = (ushort*)d_ws;               // 32*4096 bf16
  ushort* Qpk = PTb + (size_t)R2 * D;        // 4096*32 bf16
  float*  UP  = (float*)(Qpk + (size_t)D * R2);  // 16*8192*32 fp32

  hipLaunchKernelGGL(prep_kernel, dim3((R2 * D) / 256), dim3(256), 0, stream,
                     A, B, A0, B0, PTb, Qpk);
  hipLaunchKernelGGL(s1_kernel, dim3(1024), dim3(256), 0, stream,
                     x, PTb, UP);
  hipLaunchKernelGGL(s2_kernel, dim3(1024), dim3(256), 0, stream,
                     UP, Qpk, out);
}

// Round 6
// 66.681 us; speedup vs baseline: 3.3266x; 1.1997x over previous
//
#include <hip/hip_runtime.h>

// out = x @ ((B@A - B0@A0) * s)  ==  ((x@[B|-B0]) @ [A;A0]) * s,  s = 1.
// x[8192][4096] fp32, A/A0[16][4096], B/B0[4096][16].
// Both GEMMs on mfma_f32_16x16x32_bf16 (fp32 accumulate). Stage 1 now keeps
// the full K=4096 accumulation inside one block (4 waves x 1024 k each,
// LDS-reduced) and writes the final u[8192][32] fp32 (1 MB) -- no split-K
// partial round-trip.
#define N_TOK 8192
#define D     4096
#define RLO   16
#define R2    32

typedef __bf16  bf16x8  __attribute__((ext_vector_type(8)));
typedef short   short8v __attribute__((ext_vector_type(8)));
typedef float   f32x4   __attribute__((ext_vector_type(4)));

__device__ __forceinline__ short bf1(float f) {
  __bf16 b = (__bf16)f;
  return __builtin_bit_cast(short, b);
}

__device__ __forceinline__ short8v cvt8(float4 lo, float4 hi) {
  bf16x8 b;
  b[0] = (__bf16)lo.x; b[1] = (__bf16)lo.y; b[2] = (__bf16)lo.z; b[3] = (__bf16)lo.w;
  b[4] = (__bf16)hi.x; b[5] = (__bf16)hi.y; b[6] = (__bf16)hi.z; b[7] = (__bf16)hi.w;
  return __builtin_bit_cast(short8v, b);
}

// d_ws layout: PTb [32][4096] bf16 (256 KB) | Qpk [4096][32] bf16 (256 KB)
//              | u [8192][32] fp32 (1 MB)

__global__ __launch_bounds__(256) void prep_kernel(
    const float* __restrict__ A, const float* __restrict__ B,
    const float* __restrict__ A0, const float* __restrict__ B0,
    ushort* __restrict__ PTb, ushort* __restrict__ Qpk) {
  int idx = blockIdx.x * 256 + threadIdx.x;   // 0 .. 32*4096-1
  int r = idx >> 12;
  int k = idx & (D - 1);
  float pt, q;
  if (r < RLO) {
    pt = B[k * RLO + r];
    q  = A[r * D + k];
  } else {
    pt = -B0[k * RLO + (r - RLO)];
    q  = A0[(r - RLO) * D + k];
  }
  PTb[idx] = (ushort)bf1(pt);                 // [r][k], k contiguous
  Qpk[(size_t)k * R2 + r] = (ushort)bf1(q);   // [j][r], r contiguous
}

// Stage 1: u[i][r] = sum_k x[i][k] * P[k][r].
// Block: 16 rows, 4 waves; wave w accumulates k in [w*1024, w*1024+1024)
// via 32 MFMA k-steps; the 4 wave-partials are LDS-reduced.
// A-frag lane l: x[row0 + (l&15)][kb + (l>>4)*8 + j]
// B-frag lane l: PTb[(l&15)][kb + (l>>4)*8 + j]   (b1: rows 16..31)
__global__ __launch_bounds__(256) void s1_kernel(
    const float* __restrict__ x, const ushort* __restrict__ PTb,
    float* __restrict__ u) {
  __shared__ float red[4][16][R2 + 2];   // +2 pad -> conflict-free epilogue
  const int tid  = threadIdx.x;
  const int w    = tid >> 6;
  const int lane = tid & 63;
  const int l16  = lane & 15;
  const int kg   = lane >> 4;
  const int row0 = blockIdx.x * 16;
  const int kb   = w * 1024 + kg * 8;

  const float*  xp = x   + (size_t)(row0 + l16) * D + kb;
  const ushort* pb0 = PTb + (size_t)l16 * D + kb;
  const ushort* pb1 = pb0 + (size_t)16 * D;

  f32x4 acc0 = {0.f, 0.f, 0.f, 0.f};
  f32x4 acc1 = {0.f, 0.f, 0.f, 0.f};

#pragma unroll
  for (int s = 0; s < 32; ++s) {
    const int ko = s * 32;
    const float4 alo = *(const float4*)(xp + ko);
    const float4 ahi = *(const float4*)(xp + ko + 4);
    const short8v b0 = *(const short8v*)(pb0 + ko);
    const short8v b1 = *(const short8v*)(pb1 + ko);
    const short8v a  = cvt8(alo, ahi);
    acc0 = __builtin_amdgcn_mfma_f32_16x16x32_bf16(a, b0, acc0, 0, 0, 0);
    acc1 = __builtin_amdgcn_mfma_f32_16x16x32_bf16(a, b1, acc1, 0, 0, 0);
  }

  // D-frag: col = lane&15 (= r), row = (lane>>4)*4 + j (= local x-row)
#pragma unroll
  for (int j = 0; j < 4; ++j) {
    red[w][kg * 4 + j][l16]      = acc0[j];
    red[w][kg * 4 + j][16 + l16] = acc1[j];
  }
  __syncthreads();

  // 512 cells (16 rows x 32 r); 256 threads handle 2 each; coalesced u write.
#pragma unroll
  for (int half = 0; half < 2; ++half) {
    const int idx = half * 256 + tid;
    const int row = idx >> 5;
    const int r   = idx & 31;
    const float s = red[0][row][r] + red[1][row][r] +
                    red[2][row][r] + red[3][row][r];
    u[(size_t)(row0 + row) * R2 + r] = s;
  }
}

// Stage 2: out[i][j] = sum_r u[i][r] * Q[r][j].
// Block: 32 rows x 1024 j (4 waves x 256 j). K = R2 = 32 -> one MFMA depth.
__global__ __launch_bounds__(256) void s2_kernel(
    const float* __restrict__ u, const ushort* __restrict__ Qpk,
    float* __restrict__ out) {
  __shared__ __align__(16) ushort usb[32][R2];   // u tile in bf16, 2 KB
  const int tid = threadIdx.x;
  const int rowblk = (int)blockIdx.x >> 2;       // 0..255
  const int jseg   = blockIdx.x & 3;
  const int row0 = rowblk * 32;

  {  // load 32x32 u tile (coalesced float4), convert to bf16
    const int row = tid >> 3;
    const int r4  = (tid & 7) * 4;
    const float4 v = *(const float4*)(u + (size_t)(row0 + row) * R2 + r4);
    usb[row][r4 + 0] = (ushort)bf1(v.x);
    usb[row][r4 + 1] = (ushort)bf1(v.y);
    usb[row][r4 + 2] = (ushort)bf1(v.z);
    usb[row][r4 + 3] = (ushort)bf1(v.w);
  }
  __syncthreads();

  const int w    = tid >> 6;
  const int lane = tid & 63;
  const int l16  = lane & 15;
  const int kg   = lane >> 4;
  const int jbase = jseg * 1024 + w * 256;

  const short8v ua0 = *(const short8v*)&usb[l16][kg * 8];
  const short8v ua1 = *(const short8v*)&usb[16 + l16][kg * 8];
  const f32x4 z = {0.f, 0.f, 0.f, 0.f};

#pragma unroll
  for (int jt = 0; jt < 16; ++jt) {
    const int j = jbase + jt * 16 + l16;
    const short8v qb = *(const short8v*)(Qpk + (size_t)j * R2 + kg * 8);
    const f32x4 d0 = __builtin_amdgcn_mfma_f32_16x16x32_bf16(ua0, qb, z, 0, 0, 0);
    const f32x4 d1 = __builtin_amdgcn_mfma_f32_16x16x32_bf16(ua1, qb, z, 0, 0, 0);
    float* o = out + (size_t)(row0 + kg * 4) * D + j;
#pragma unroll
    for (int jr = 0; jr < 4; ++jr) {
      o[(size_t)jr * D]        = d0[jr];
      o[(size_t)(16 + jr) * D] = d1[jr];
    }
  }
}

extern "C" void kernel_launch(void* const* d_in, const int* in_sizes, int n_in,
                              void* d_out, int out_size, void* d_ws, size_t ws_size,
                              hipStream_t stream) {
  const float* x  = (const float*)d_in[0];
  const float* A  = (const float*)d_in[1];
  const float* B  = (const float*)d_in[2];
  const float* A0 = (const float*)d_in[3];
  const float* B0 = (const float*)d_in[4];
  float* out = (float*)d_out;

  ushort* PTb = (ushort*)d_ws;               // 32*4096 bf16
  ushort* Qpk = PTb + (size_t)R2 * D;        // 4096*32 bf16
  float*  u   = (float*)(Qpk + (size_t)D * R2);  // 8192*32 fp32

  hipLaunchKernelGGL(prep_kernel, dim3((R2 * D) / 256), dim3(256), 0, stream,
                     A, B, A0, B0, PTb, Qpk);
  hipLaunchKernelGGL(s1_kernel, dim3(N_TOK / 16), dim3(256), 0, stream,
                     x, PTb, u);
  hipLaunchKernelGGL(s2_kernel, dim3((N_TOK / 32) * 4), dim3(256), 0, stream,
                     u, Qpk, out);
}

// Round 7
// 64.381 us; speedup vs baseline: 3.4455x; 1.0357x over previous
//
#include <hip/hip_runtime.h>

// out = x @ ((B@A - B0@A0) * s)  ==  ((x@[B|-B0]) @ [A;A0]) * s,  s = 1.
// x[8192][4096] fp32, A/A0[16][4096], B/B0[4096][16].
// Fully fused: the computation is row-local (u[i] depends only on x[i],
// out[i] only on u[i]), so one kernel does GEMM1 (K=4096, MFMA, LDS-reduced
// across 4 waves) and GEMM2 (K=32, one MFMA depth) per 16-row tile.
// Out stores are non-temporal so x stays L3-resident across replays.
#define N_TOK 8192
#define D     4096
#define RLO   16
#define R2    32

typedef __bf16  bf16x8  __attribute__((ext_vector_type(8)));
typedef short   short8v __attribute__((ext_vector_type(8)));
typedef float   f32x4   __attribute__((ext_vector_type(4)));

__device__ __forceinline__ short bf1(float f) {
  __bf16 b = (__bf16)f;
  return __builtin_bit_cast(short, b);
}

__device__ __forceinline__ short8v cvt8(float4 lo, float4 hi) {
  bf16x8 b;
  b[0] = (__bf16)lo.x; b[1] = (__bf16)lo.y; b[2] = (__bf16)lo.z; b[3] = (__bf16)lo.w;
  b[4] = (__bf16)hi.x; b[5] = (__bf16)hi.y; b[6] = (__bf16)hi.z; b[7] = (__bf16)hi.w;
  return __builtin_bit_cast(short8v, b);
}

// d_ws layout: PTb [32][4096] bf16 (256 KB) | Qpk [4096][32] bf16 (256 KB)

__global__ __launch_bounds__(256) void prep_kernel(
    const float* __restrict__ A, const float* __restrict__ B,
    const float* __restrict__ A0, const float* __restrict__ B0,
    ushort* __restrict__ PTb, ushort* __restrict__ Qpk) {
  int idx = blockIdx.x * 256 + threadIdx.x;   // 0 .. 32*4096-1
  int r = idx >> 12;
  int k = idx & (D - 1);
  float pt, q;
  if (r < RLO) {
    pt = B[k * RLO + r];
    q  = A[r * D + k];
  } else {
    pt = -B0[k * RLO + (r - RLO)];
    q  = A0[(r - RLO) * D + k];
  }
  PTb[idx] = (ushort)bf1(pt);                 // [r][k], k contiguous
  Qpk[(size_t)k * R2 + r] = (ushort)bf1(q);   // [j][r], r contiguous
}

// Fused: per 16-row tile.
// Phase A (GEMM1): wave w accumulates k in [w*1024, w*1024+1024) via 32 MFMA
//   k-steps; 4 wave-partials LDS-reduced; u tile -> bf16 in LDS.
// Phase B (GEMM2): wave w covers j in [w*1024, w*1024+1024): 64 MFMA tiles,
//   non-temporal dword stores.
__global__ __launch_bounds__(256) void fused_kernel(
    const float* __restrict__ x, const ushort* __restrict__ PTb,
    const ushort* __restrict__ Qpk, float* __restrict__ out) {
  __shared__ float red[4][16][R2 + 2];           // +2 pad: conflict-free reduce
  __shared__ __align__(16) ushort usb[16][R2];   // u tile in bf16, 1 KB
  const int tid  = threadIdx.x;
  const int w    = tid >> 6;
  const int lane = tid & 63;
  const int l16  = lane & 15;
  const int kg   = lane >> 4;
  const int row0 = blockIdx.x * 16;
  const int kb   = w * 1024 + kg * 8;

  // ---- Phase A: u[row0..row0+15][0..31] ----
  const float*  xp  = x   + (size_t)(row0 + l16) * D + kb;
  const ushort* pb0 = PTb + (size_t)l16 * D + kb;
  const ushort* pb1 = pb0 + (size_t)16 * D;

  f32x4 acc0 = {0.f, 0.f, 0.f, 0.f};
  f32x4 acc1 = {0.f, 0.f, 0.f, 0.f};

#pragma unroll
  for (int s = 0; s < 32; ++s) {
    const int ko = s * 32;
    const float4 alo = *(const float4*)(xp + ko);
    const float4 ahi = *(const float4*)(xp + ko + 4);
    const short8v b0 = *(const short8v*)(pb0 + ko);
    const short8v b1 = *(const short8v*)(pb1 + ko);
    const short8v a  = cvt8(alo, ahi);
    acc0 = __builtin_amdgcn_mfma_f32_16x16x32_bf16(a, b0, acc0, 0, 0, 0);
    acc1 = __builtin_amdgcn_mfma_f32_16x16x32_bf16(a, b1, acc1, 0, 0, 0);
  }

  // D-frag: col = lane&15 (= r), row = (lane>>4)*4 + j (= local x-row)
#pragma unroll
  for (int j = 0; j < 4; ++j) {
    red[w][kg * 4 + j][l16]      = acc0[j];
    red[w][kg * 4 + j][16 + l16] = acc1[j];
  }
  __syncthreads();

  // 512 cells (16 rows x 32 r); 256 threads handle 2 each; sum 4 waves -> bf16
#pragma unroll
  for (int half = 0; half < 2; ++half) {
    const int idx = half * 256 + tid;
    const int row = idx >> 5;
    const int r   = idx & 31;
    const float s = red[0][row][r] + red[1][row][r] +
                    red[2][row][r] + red[3][row][r];
    usb[row][r] = (ushort)bf1(s);
  }
  __syncthreads();

  // ---- Phase B: out[row0..row0+15][:] = u_tile @ Q ----
  // A-frag (constant over j): lane l -> u[l&15][(l>>4)*8 + t]
  const short8v ua = *(const short8v*)&usb[l16][kg * 8];
  const f32x4 z = {0.f, 0.f, 0.f, 0.f};
  const int jbase = w * 1024;

#pragma unroll 8
  for (int jt = 0; jt < 64; ++jt) {
    const int j = jbase + jt * 16 + l16;
    const short8v qb = *(const short8v*)(Qpk + (size_t)j * R2 + kg * 8);
    const f32x4 d = __builtin_amdgcn_mfma_f32_16x16x32_bf16(ua, qb, z, 0, 0, 0);
    float* o = out + (size_t)(row0 + kg * 4) * D + j;
#pragma unroll
    for (int jr = 0; jr < 4; ++jr)
      __builtin_nontemporal_store(d[jr], o + (size_t)jr * D);
  }
}

extern "C" void kernel_launch(void* const* d_in, const int* in_sizes, int n_in,
                              void* d_out, int out_size, void* d_ws, size_t ws_size,
                              hipStream_t stream) {
  const float* x  = (const float*)d_in[0];
  const float* A  = (const float*)d_in[1];
  const float* B  = (const float*)d_in[2];
  const float* A0 = (const float*)d_in[3];
  const float* B0 = (const float*)d_in[4];
  float* out = (float*)d_out;

  ushort* PTb = (ushort*)d_ws;               // 32*4096 bf16
  ushort* Qpk = PTb + (size_t)R2 * D;        // 4096*32 bf16

  hipLaunchKernelGGL(prep_kernel, dim3((R2 * D) / 256), dim3(256), 0, stream,
                     A, B, A0, B0, PTb, Qpk);
  hipLaunchKernelGGL(fused_kernel, dim3(N_TOK / 16), dim3(256), 0, stream,
                     x, PTb, Qpk, out);
}